// Round 1
// baseline (3430.863 us; speedup 1.0000x reference)
//
#include <hip/hip_runtime.h>
#include <hip/hip_bf16.h>

#define B_ 128
#define T_ 64
#define H_ 256
#define E_ 256
#define L_ 512
#define V_ 30522
#define EOS_ 2

typedef __attribute__((ext_vector_type(8))) short bf16x8;
typedef __attribute__((ext_vector_type(4))) float f32x4;

__device__ __forceinline__ float4 ld4(const float* p) { return *(const float4*)p; }

// ---------------------------------------------------------------------------
// init: h_init = z @ W_lat^T + b_lat  -> h0buf[1], h1buf[1]; c0=c1=0
// ---------------------------------------------------------------------------
__global__ __launch_bounds__(256) void init_kernel(
    const float* __restrict__ z, const float* __restrict__ W_lat,
    const float* __restrict__ b_lat,
    float* __restrict__ h0buf, float* __restrict__ h1buf,
    float* __restrict__ c0, float* __restrict__ c1) {
  int b = blockIdx.x;   // 0..127
  int h = threadIdx.x;  // 0..255
  const float* zr = z + (size_t)b * L_;
  const float* wr = W_lat + (size_t)h * L_;
  float acc = b_lat[h];
  #pragma unroll 4
  for (int l = 0; l < L_; l += 4) {
    float4 zv = ld4(zr + l);
    float4 wv = ld4(wr + l);
    acc += zv.x * wv.x + zv.y * wv.y + zv.z * wv.z + zv.w * wv.w;
  }
  int idx = b * H_ + h;
  h0buf[B_ * H_ + idx] = acc;  // buffer 1 (read at step 0)
  h1buf[B_ * H_ + idx] = acc;
  c0[idx] = 0.f;
  c1[idx] = 0.f;
}

// ---------------------------------------------------------------------------
// one LSTM cell column: compute gates for (b-row given by xrow/hrow, col h)
// ---------------------------------------------------------------------------
__device__ __forceinline__ void lstm_col(
    const float* __restrict__ xrow, const float* __restrict__ hrow,
    const float* __restrict__ W_ih, const float* __restrict__ W_hh,
    const float* __restrict__ b_ih, const float* __restrict__ b_hh,
    int h, float c_in, float* h_out, float* c_out) {
  float ai = b_ih[h]          + b_hh[h];
  float af = b_ih[H_ + h]     + b_hh[H_ + h];
  float ag = b_ih[2 * H_ + h] + b_hh[2 * H_ + h];
  float ao = b_ih[3 * H_ + h] + b_hh[3 * H_ + h];
  {
    const float* wi = W_ih + (size_t)h * E_;
    const float* wf = W_ih + (size_t)(H_ + h) * E_;
    const float* wg = W_ih + (size_t)(2 * H_ + h) * E_;
    const float* wo = W_ih + (size_t)(3 * H_ + h) * E_;
    #pragma unroll 4
    for (int e = 0; e < E_; e += 4) {
      float4 x = ld4(xrow + e);
      float4 vi = ld4(wi + e), vf = ld4(wf + e), vg = ld4(wg + e), vo = ld4(wo + e);
      ai += x.x * vi.x + x.y * vi.y + x.z * vi.z + x.w * vi.w;
      af += x.x * vf.x + x.y * vf.y + x.z * vf.z + x.w * vf.w;
      ag += x.x * vg.x + x.y * vg.y + x.z * vg.z + x.w * vg.w;
      ao += x.x * vo.x + x.y * vo.y + x.z * vo.z + x.w * vo.w;
    }
  }
  {
    const float* wi = W_hh + (size_t)h * H_;
    const float* wf = W_hh + (size_t)(H_ + h) * H_;
    const float* wg = W_hh + (size_t)(2 * H_ + h) * H_;
    const float* wo = W_hh + (size_t)(3 * H_ + h) * H_;
    #pragma unroll 4
    for (int e = 0; e < H_; e += 4) {
      float4 x = ld4(hrow + e);
      float4 vi = ld4(wi + e), vf = ld4(wf + e), vg = ld4(wg + e), vo = ld4(wo + e);
      ai += x.x * vi.x + x.y * vi.y + x.z * vi.z + x.w * vi.w;
      af += x.x * vf.x + x.y * vf.y + x.z * vf.z + x.w * vf.w;
      ag += x.x * vg.x + x.y * vg.y + x.z * vg.z + x.w * vg.w;
      ao += x.x * vo.x + x.y * vo.y + x.z * vo.z + x.w * vo.w;
    }
  }
  float ig = 1.f / (1.f + expf(-ai));
  float fg = 1.f / (1.f + expf(-af));
  float gg = tanhf(ag);
  float og = 1.f / (1.f + expf(-ao));
  float cn = fg * c_in + ig * gg;
  *c_out = cn;
  *h_out = og * tanhf(cn);
}

// ---------------------------------------------------------------------------
// fused lagged step: blocks [0,128) -> layer0 at step t (t < T)
//                    blocks [128,256) -> layer1 at step t-1 (t >= 1)
// h0buf/h1buf are double buffered [2][B][H]; layer L step s writes buf s&1,
// reads buf (s+1)&1.
// ---------------------------------------------------------------------------
__global__ __launch_bounds__(256) void lstm_step(
    int t,
    const int* __restrict__ target, const float* __restrict__ emb,
    const float* __restrict__ W_ih0, const float* __restrict__ W_hh0,
    const float* __restrict__ b_ih0, const float* __restrict__ b_hh0,
    const float* __restrict__ W_ih1, const float* __restrict__ W_hh1,
    const float* __restrict__ b_ih1, const float* __restrict__ b_hh1,
    float* __restrict__ h0buf, float* __restrict__ c0,
    float* __restrict__ h1buf, float* __restrict__ c1,
    __hip_bfloat16* __restrict__ hs) {
  int blk = blockIdx.x;
  int b_local = threadIdx.x & 31;
  int h_local = threadIdx.x >> 5;
  if (blk < 128) {
    if (t >= T_) return;
    int b = (blk & 3) * 32 + b_local;
    int h = (blk >> 2) * 8 + h_local;
    int tok = (t == 0) ? EOS_ : target[b * T_ + t - 1];
    const float* xrow = emb + (size_t)tok * E_;
    const float* hrow = h0buf + ((t + 1) & 1) * (B_ * H_) + b * H_;
    int idx = b * H_ + h;
    float hn, cn;
    lstm_col(xrow, hrow, W_ih0, W_hh0, b_ih0, b_hh0, h, c0[idx], &hn, &cn);
    c0[idx] = cn;
    h0buf[(t & 1) * (B_ * H_) + idx] = hn;
  } else {
    if (t == 0) return;
    int s = t - 1;
    int blk1 = blk - 128;
    int b = (blk1 & 3) * 32 + b_local;
    int h = (blk1 >> 2) * 8 + h_local;
    const float* xrow = h0buf + (s & 1) * (B_ * H_) + b * H_;   // h0[s]
    const float* hrow = h1buf + ((s + 1) & 1) * (B_ * H_) + b * H_;
    int idx = b * H_ + h;
    float hn, cn;
    lstm_col(xrow, hrow, W_ih1, W_hh1, b_ih1, b_hh1, h, c1[idx], &hn, &cn);
    c1[idx] = cn;
    h1buf[(s & 1) * (B_ * H_) + idx] = hn;
    hs[(size_t)s * B_ * H_ + idx] = __float2bfloat16(hn);
  }
}

// ---------------------------------------------------------------------------
// logits = hs @ W_out^T + b_out.  A = hs [8192][256] bf16 (row m = t*128+b),
// B^T = W_out [V][256] f32 (converted to bf16 inline).  Output [B][T][V] f32.
// 128x128 tile per block, 4 waves, each wave 64x64 via 4x4 16x16x32 frags.
// ---------------------------------------------------------------------------
__global__ __launch_bounds__(256) void gemm_out(
    const __hip_bfloat16* __restrict__ hs,
    const float* __restrict__ Wout, const float* __restrict__ bout,
    float* __restrict__ out) {
  int lane = threadIdx.x & 63;
  int w = threadIdx.x >> 6;
  int wr = w >> 1, wc = w & 1;
  int m_base = blockIdx.x * 128 + wr * 64;
  int n_base = blockIdx.y * 128 + wc * 64;
  int row_in = lane & 15;
  int kgrp = lane >> 4;  // 0..3

  f32x4 acc[4][4];
  #pragma unroll
  for (int i = 0; i < 4; ++i)
    #pragma unroll
    for (int j = 0; j < 4; ++j) acc[i][j] = (f32x4){0.f, 0.f, 0.f, 0.f};

  for (int kb = 0; kb < 8; ++kb) {
    int k0 = kb * 32 + kgrp * 8;
    bf16x8 a[4], bb[4];
    #pragma unroll
    for (int mi = 0; mi < 4; ++mi) {
      const __hip_bfloat16* p = hs + (size_t)(m_base + mi * 16 + row_in) * H_ + k0;
      a[mi] = *(const bf16x8*)p;
    }
    #pragma unroll
    for (int ni = 0; ni < 4; ++ni) {
      int v = n_base + ni * 16 + row_in;
      union { bf16x8 v8; __hip_bfloat16 e[8]; } u;
      if (v < V_) {
        const float* p = Wout + (size_t)v * H_ + k0;
        float4 lo = ld4(p), hi = ld4(p + 4);
        u.e[0] = __float2bfloat16(lo.x); u.e[1] = __float2bfloat16(lo.y);
        u.e[2] = __float2bfloat16(lo.z); u.e[3] = __float2bfloat16(lo.w);
        u.e[4] = __float2bfloat16(hi.x); u.e[5] = __float2bfloat16(hi.y);
        u.e[6] = __float2bfloat16(hi.z); u.e[7] = __float2bfloat16(hi.w);
      } else {
        bf16x8 zz = {0, 0, 0, 0, 0, 0, 0, 0};
        u.v8 = zz;
      }
      bb[ni] = u.v8;
    }
    #pragma unroll
    for (int mi = 0; mi < 4; ++mi)
      #pragma unroll
      for (int ni = 0; ni < 4; ++ni)
        acc[mi][ni] = __builtin_amdgcn_mfma_f32_16x16x32_bf16(a[mi], bb[ni], acc[mi][ni], 0, 0, 0);
  }

  #pragma unroll
  for (int ni = 0; ni < 4; ++ni) {
    int v = n_base + ni * 16 + row_in;
    if (v >= V_) continue;
    float bias = bout[v];
    #pragma unroll
    for (int mi = 0; mi < 4; ++mi) {
      #pragma unroll
      for (int r = 0; r < 4; ++r) {
        int m = m_base + mi * 16 + kgrp * 4 + r;
        int tt = m >> 7;       // row m = t*128 + b
        int bb_ = m & 127;
        out[((size_t)bb_ * T_ + tt) * V_ + v] = acc[mi][ni][r] + bias;
      }
    }
  }
}

// ---------------------------------------------------------------------------
extern "C" void kernel_launch(void* const* d_in, const int* in_sizes, int n_in,
                              void* d_out, int out_size, void* d_ws, size_t ws_size,
                              hipStream_t stream) {
  const float* z     = (const float*)d_in[0];
  const int*   targ  = (const int*)d_in[1];
  const float* emb   = (const float*)d_in[2];
  const float* W_ih0 = (const float*)d_in[3];
  const float* W_hh0 = (const float*)d_in[4];
  const float* b_ih0 = (const float*)d_in[5];
  const float* b_hh0 = (const float*)d_in[6];
  const float* W_ih1 = (const float*)d_in[7];
  const float* W_hh1 = (const float*)d_in[8];
  const float* b_ih1 = (const float*)d_in[9];
  const float* b_hh1 = (const float*)d_in[10];
  const float* W_out = (const float*)d_in[11];
  const float* b_out = (const float*)d_in[12];
  const float* W_lat = (const float*)d_in[13];
  const float* b_lat = (const float*)d_in[14];
  float* out = (float*)d_out;

  char* ws = (char*)d_ws;
  float* h0buf = (float*)(ws);                       // 2*B*H f32 = 256 KB
  float* h1buf = (float*)(ws + 262144);              // 2*B*H f32 = 256 KB
  float* c0    = (float*)(ws + 524288);              // B*H f32 = 128 KB
  float* c1    = (float*)(ws + 655360);              // B*H f32 = 128 KB
  __hip_bfloat16* hs = (__hip_bfloat16*)(ws + 786432);  // T*B*H bf16 = 4 MB

  init_kernel<<<128, 256, 0, stream>>>(z, W_lat, b_lat, h0buf, h1buf, c0, c1);
  for (int t = 0; t <= T_; ++t) {
    lstm_step<<<256, 256, 0, stream>>>(t, targ, emb,
                                       W_ih0, W_hh0, b_ih0, b_hh0,
                                       W_ih1, W_hh1, b_ih1, b_hh1,
                                       h0buf, c0, h1buf, c1, hs);
  }
  dim3 grid(64, 239);
  gemm_out<<<grid, 256, 0, stream>>>(hs, W_out, b_out, out);
}